// Round 4
// baseline (190.460 us; speedup 1.0000x reference)
//
#include <hip/hip_runtime.h>
#include <hip/hip_bf16.h>

#define NE 32
#define MM 256        // tokens per expert
#define DM 1024       // dmodel
#define ES 2048       // expert size

typedef __attribute__((ext_vector_type(8))) short short8;
typedef __attribute__((ext_vector_type(4))) float f32x4;
typedef unsigned int uint32;
typedef unsigned long long u64;
typedef unsigned short u16;

// One-instruction packed f32->bf16 (RNE). D[15:0]=bf16(a), D[31:16]=bf16(b).
__device__ __forceinline__ uint32 cvt_pk_bf16(float a, float b) {
    uint32 r;
    asm("v_cvt_pk_bf16_f32 %0, %1, %2" : "=v"(r) : "v"(a), "v"(b));
    return r;
}
__device__ __forceinline__ u64 pack4(float a, float b, float c, float d) {
    return (u64)cvt_pk_bf16(a, b) | ((u64)cvt_pk_bf16(c, d) << 32);
}

// Async global->LDS, 16B per lane. LDS dest is wave-uniform base + lane*16.
__device__ __forceinline__ void gl_lds16(const void* g, void* l) {
    __builtin_amdgcn_global_load_lds(
        (const __attribute__((address_space(1))) uint32*)g,
        (__attribute__((address_space(3))) uint32*)l, 16, 0, 0);
}

// B LDS tile: bf16 [n][k], 128B rows, 16B-slot XOR swizzle (verified r1-r3).
__device__ __forceinline__ int b_off(int n, int k) {
    int X = ((n >> 2) & 7) ^ ((n & 3) << 1);
    return n * 128 + ((((k >> 3) ^ X) & 7) << 4) + (((k >> 2) & 1) << 3);
}

// Streaming f32 -> bf16 convert (for x). 16B loads / 8B stores per thread-iter.
__global__ __launch_bounds__(256) void cvt_bf16(const float* __restrict__ x,
                                                u16* __restrict__ xb, int n4) {
    int i = blockIdx.x * blockDim.x + threadIdx.x;
    int stride = gridDim.x * blockDim.x;
    for (; i < n4; i += stride) {
        float4 v = ((const float4*)x)[i];
        ((u64*)xb)[i] = pack4(v.x, v.y, v.z, v.w);
    }
}

// Grouped GEMM: C[e] = act(A[e] @ B[e]) over NE experts.
// A: bf16 [NE*MM][K], staged via global_load_lds with source-side granule
//    swizzle s' = s ^ (m&7)  (linear LDS dest, swizzled read -- rule #21).
// B: [NE][K][N] f32, prefetched to regs one K-step ahead, cvt+transposed to LDS.
// Double-buffered LDS, ONE barrier per K-step; prefetch in flight across compute.
template<int N, int K, bool RELU, typename CT>
__global__ __launch_bounds__(256) void ec_gemm(
    const u16* __restrict__ A,
    const float* __restrict__ B,
    CT* __restrict__ C)
{
    constexpr int BM = 128, BN = 128, BK = 64;
    constexpr int MT = MM / BM;   // 2
    constexpr int NT = N / BN;
    constexpr int NSTEP = K / BK;

    int bid = blockIdx.x;
    int e   = bid / (MT * NT);
    int rem = bid % (MT * NT);
    int mt  = rem / NT;
    int nt  = rem % NT;

    const u16*   Ae = A + (size_t)(e * MM + mt * BM) * K;
    const float* Be = B + (size_t)e * K * N + (size_t)nt * BN;
    CT*          Ce = C + (size_t)(e * MM + mt * BM) * N + (size_t)nt * BN;

    __shared__ char AsB[2][BM * BK * 2];   // 2 x 16KB bf16, linear (gload dest)
    __shared__ char BsB[2][BN * BK * 2];   // 2 x 16KB bf16 [n][k] swizzled

    const int t    = threadIdx.x;
    const int lane = t & 63;
    const int w    = t >> 6;
    const int wm   = (w >> 1) * 64;
    const int wn   = (w & 1) * 64;
    const int lr   = lane & 15;
    const int lg   = lane >> 4;

    // B staging thread mapping (verified r1-r3)
    const int bn4 = (t & 31) * 4;     // n quad
    const int bkb = (t >> 5) * 4;     // k quad base; +32 for group 1

    f32x4  acc[4][4] = {};
    float4 br[2][4];                  // prefetched B: 2 k-groups x 4 rows

    auto gloadA = [&](int kt, int buf) {
        #pragma unroll
        for (int r = 0; r < 4; ++r) {
            int reg = w * 4 + r;
            int m   = reg * 8 + (lane >> 3);
            int s   = (lane & 7) ^ (m & 7);
            const u16* g = Ae + (size_t)m * K + kt + s * 8;
            gl_lds16(g, AsB[buf] + reg * 1024);
        }
    };
    auto loadB = [&](int kt) {
        #pragma unroll
        for (int g = 0; g < 2; ++g) {
            int k4 = g * 32 + bkb;
            const float* Bk = Be + (size_t)(kt + k4) * N + bn4;
            br[g][0] = *(const float4*)(Bk);
            br[g][1] = *(const float4*)(Bk + N);
            br[g][2] = *(const float4*)(Bk + 2 * (size_t)N);
            br[g][3] = *(const float4*)(Bk + 3 * (size_t)N);
        }
    };
    auto writeB = [&](int buf) {
        #pragma unroll
        for (int g = 0; g < 2; ++g) {
            int k4 = g * 32 + bkb;
            *(u64*)(BsB[buf] + b_off(bn4 + 0, k4)) = pack4(br[g][0].x, br[g][1].x, br[g][2].x, br[g][3].x);
            *(u64*)(BsB[buf] + b_off(bn4 + 1, k4)) = pack4(br[g][0].y, br[g][1].y, br[g][2].y, br[g][3].y);
            *(u64*)(BsB[buf] + b_off(bn4 + 2, k4)) = pack4(br[g][0].z, br[g][1].z, br[g][2].z, br[g][3].z);
            *(u64*)(BsB[buf] + b_off(bn4 + 3, k4)) = pack4(br[g][0].w, br[g][1].w, br[g][2].w, br[g][3].w);
        }
    };
    auto readA = [&](int i, int k, int buf) -> short8 {
        int m = wm + i * 16 + lr;
        int s = ((k >> 3) ^ (m & 7)) & 7;
        return *(const short8*)(AsB[buf] + m * 128 + s * 16);
    };

    // ---- prologue: stage tile 0 into buf 0 ----
    loadB(0);
    gloadA(0, 0);
    writeB(0);         // waits br via register-dep waitcnt
    __syncthreads();   // drains gloadA (vmcnt) + writeB (lgkm)

    for (int ks = 0; ks < NSTEP; ++ks) {
        const int  c  = ks & 1;
        const bool pf = (ks + 1 < NSTEP);
        // issue next tile's loads FIRST -- in flight across the whole compute
        if (pf) { gloadA((ks + 1) * BK, c ^ 1); loadB((ks + 1) * BK); }

        #pragma unroll
        for (int kk = 0; kk < 2; ++kk) {
            int k = kk * 32 + lg * 8;
            short8 af[4], bfr[4];
            #pragma unroll
            for (int i = 0; i < 4; ++i) af[i] = readA(i, k, c);
            #pragma unroll
            for (int j = 0; j < 4; ++j)
                bfr[j] = *(const short8*)(BsB[c] + b_off(wn + j * 16 + lr, k));
            #pragma unroll
            for (int i = 0; i < 4; ++i)
                #pragma unroll
                for (int j = 0; j < 4; ++j)
                    acc[i][j] = __builtin_amdgcn_mfma_f32_16x16x32_bf16(af[i], bfr[j], acc[i][j], 0, 0, 0);
        }
        // write next B tile to the other buffer (no barrier needed: disjoint buf)
        if (pf) writeB(c ^ 1);
        __syncthreads();   // single barrier per K-step
    }

    // ---- epilogue: C/D layout col=lane&15, row=(lane>>4)*4+reg (verified) ----
    #pragma unroll
    for (int i = 0; i < 4; ++i) {
        #pragma unroll
        for (int rr = 0; rr < 4; ++rr) {
            int row = wm + i * 16 + lg * 4 + rr;
            CT* Cp = Ce + (size_t)row * N + wn + lr;
            if constexpr (sizeof(CT) == 2) {
                #pragma unroll
                for (int jp = 0; jp < 2; ++jp) {
                    float v0 = acc[i][2 * jp + 0][rr];
                    float v1 = acc[i][2 * jp + 1][rr];
                    if constexpr (RELU) {
                        v0 = v0 > 0.0f ? v0 : 0.0f;
                        v1 = v1 > 0.0f ? v1 : 0.0f;
                    }
                    uint32 p = cvt_pk_bf16(v0, v1);
                    ((u16*)Cp)[(2 * jp + 0) * 16] = (u16)(p & 0xffffu);
                    ((u16*)Cp)[(2 * jp + 1) * 16] = (u16)(p >> 16);
                }
            } else {
                #pragma unroll
                for (int j = 0; j < 4; ++j) {
                    float v = acc[i][j][rr];
                    if constexpr (RELU) v = v > 0.0f ? v : 0.0f;
                    ((float*)Cp)[j * 16] = v;
                }
            }
        }
    }
}

extern "C" void kernel_launch(void* const* d_in, const int* in_sizes, int n_in,
                              void* d_out, int out_size, void* d_ws, size_t ws_size,
                              hipStream_t stream) {
    const float* x    = (const float*)d_in[0];
    // d_in[1] = gate: dead code in the reference output -- unused.
    const float* lin1 = (const float*)d_in[2];
    const float* lin2 = (const float*)d_in[3];
    float* out = (float*)d_out;

    u16* h  = (u16*)d_ws;                                   // 33.6 MB bf16
    u16* xb = (u16*)((char*)d_ws + (size_t)36 * 1024 * 1024); // 16.8 MB bf16

    dim3 blk(256);
    // x: f32 -> bf16 once (bit-identical RNE to per-tile conversion)
    cvt_bf16<<<2048, blk, 0, stream>>>(x, xb, NE * MM * DM / 4);
    // GEMM1: h = relu(x @ W1), per expert 256x2048, K=1024
    ec_gemm<ES, DM, true,  u16  ><<<NE * (MM/128) * (ES/128), blk, 0, stream>>>(xb, lin1, h);
    // GEMM2: out = h @ W2, per expert 256x1024, K=2048
    ec_gemm<DM, ES, false, float><<<NE * (MM/128) * (DM/128), blk, 0, stream>>>(h, lin2, out);
}

// Round 5
// 181.424 us; speedup vs baseline: 1.0498x; 1.0498x over previous
//
#include <hip/hip_runtime.h>
#include <hip/hip_bf16.h>

#define NE 32
#define MM 256        // tokens per expert
#define DM 1024       // dmodel
#define ES 2048       // expert size

typedef __attribute__((ext_vector_type(8))) short short8;
typedef __attribute__((ext_vector_type(4))) float f32x4;
typedef unsigned int uint32;
typedef unsigned long long u64;
typedef unsigned short u16;

// One-instruction packed f32->bf16 (RNE). D[15:0]=bf16(a), D[31:16]=bf16(b).
__device__ __forceinline__ uint32 cvt_pk_bf16(float a, float b) {
    uint32 r;
    asm("v_cvt_pk_bf16_f32 %0, %1, %2" : "=v"(r) : "v"(a), "v"(b));
    return r;
}
__device__ __forceinline__ u64 pack4(float a, float b, float c, float d) {
    return (u64)cvt_pk_bf16(a, b) | ((u64)cvt_pk_bf16(c, d) << 32);
}

// Async global->LDS, 16B per lane. LDS dest is wave-uniform base + lane*16.
__device__ __forceinline__ void gl_lds16(const void* g, void* l) {
    __builtin_amdgcn_global_load_lds(
        (const __attribute__((address_space(1))) uint32*)g,
        (__attribute__((address_space(3))) uint32*)l, 16, 0, 0);
}

// B LDS tile: bf16 [n][k], 128B rows, 16B-slot XOR swizzle (verified r1-r4).
__device__ __forceinline__ int b_off(int n, int k) {
    int X = ((n >> 2) & 7) ^ ((n & 3) << 1);
    return n * 128 + ((((k >> 3) ^ X) & 7) << 4) + (((k >> 2) & 1) << 3);
}

// Streaming f32 -> bf16 convert (for x). 16B loads / 8B stores per thread-iter.
__global__ __launch_bounds__(256) void cvt_bf16(const float* __restrict__ x,
                                                u16* __restrict__ xb, int n4) {
    int i = blockIdx.x * blockDim.x + threadIdx.x;
    int stride = gridDim.x * blockDim.x;
    for (; i < n4; i += stride) {
        float4 v = ((const float4*)x)[i];
        ((u64*)xb)[i] = pack4(v.x, v.y, v.z, v.w);
    }
}

// Grouped GEMM: C[e] = act(A[e] @ B[e]) over NE experts.
// A: bf16 [NE*MM][K], staged via global_load_lds, source-side granule swizzle.
// B: [NE][K][N] f32, prefetched to regs one K-step ahead, cvt+transposed to LDS.
// Double-buffered LDS, one barrier per K-step.
// XCD-aware block mapping: all NT column-tiles of an A-panel (e,mt) map to ONE
// XCD (A/h panel fetched once per chip, not 8x), and mt-pairs sharing a W panel
// are consecutive on the same XCD and co-resident (W fetched once).
template<int N, int K, bool RELU, typename CT>
__global__ __launch_bounds__(256) void ec_gemm(
    const u16* __restrict__ A,
    const float* __restrict__ B,
    CT* __restrict__ C)
{
    constexpr int BM = 128, BN = 128, BK = 64;
    constexpr int MT = MM / BM;   // 2
    constexpr int NT = N / BN;
    constexpr int NSTEP = K / BK;
    constexpr int NP  = NE * MT;  // 64 panels
    constexpr int PPX = NP / 8;   // 8 panels per XCD

    // ---- XCD-aware decode: bid%8 = XCD (hardware round-robin) ----
    int bid   = blockIdx.x;
    int xcd   = bid & 7;
    int local = bid >> 3;               // 0 .. NP*NT/8 - 1
    int p     = xcd * PPX + local / NT; // panel, grouped per XCD
    int nt    = local % NT;
    int e     = p >> 1;
    int mt    = p & 1;

    const u16*   Ae = A + (size_t)(e * MM + mt * BM) * K;
    const float* Be = B + (size_t)e * K * N + (size_t)nt * BN;
    CT*          Ce = C + (size_t)(e * MM + mt * BM) * N + (size_t)nt * BN;

    __shared__ char AsB[2][BM * BK * 2];   // 2 x 16KB bf16, linear (gload dest)
    __shared__ char BsB[2][BN * BK * 2];   // 2 x 16KB bf16 [n][k] swizzled

    const int t    = threadIdx.x;
    const int lane = t & 63;
    const int w    = t >> 6;
    const int wm   = (w >> 1) * 64;
    const int wn   = (w & 1) * 64;
    const int lr   = lane & 15;
    const int lg   = lane >> 4;

    // B staging thread mapping (verified r1-r4)
    const int bn4 = (t & 31) * 4;     // n quad
    const int bkb = (t >> 5) * 4;     // k quad base; +32 for group 1

    f32x4  acc[4][4] = {};
    float4 br[2][4];                  // prefetched B: 2 k-groups x 4 rows

    auto gloadA = [&](int kt, int buf) {
        #pragma unroll
        for (int r = 0; r < 4; ++r) {
            int reg = w * 4 + r;
            int m   = reg * 8 + (lane >> 3);
            int s   = (lane & 7) ^ (m & 7);
            const u16* g = Ae + (size_t)m * K + kt + s * 8;
            gl_lds16(g, AsB[buf] + reg * 1024);
        }
    };
    auto loadB = [&](int kt) {
        #pragma unroll
        for (int g = 0; g < 2; ++g) {
            int k4 = g * 32 + bkb;
            const float* Bk = Be + (size_t)(kt + k4) * N + bn4;
            br[g][0] = *(const float4*)(Bk);
            br[g][1] = *(const float4*)(Bk + N);
            br[g][2] = *(const float4*)(Bk + 2 * (size_t)N);
            br[g][3] = *(const float4*)(Bk + 3 * (size_t)N);
        }
    };
    auto writeB = [&](int buf) {
        #pragma unroll
        for (int g = 0; g < 2; ++g) {
            int k4 = g * 32 + bkb;
            *(u64*)(BsB[buf] + b_off(bn4 + 0, k4)) = pack4(br[g][0].x, br[g][1].x, br[g][2].x, br[g][3].x);
            *(u64*)(BsB[buf] + b_off(bn4 + 1, k4)) = pack4(br[g][0].y, br[g][1].y, br[g][2].y, br[g][3].y);
            *(u64*)(BsB[buf] + b_off(bn4 + 2, k4)) = pack4(br[g][0].z, br[g][1].z, br[g][2].z, br[g][3].z);
            *(u64*)(BsB[buf] + b_off(bn4 + 3, k4)) = pack4(br[g][0].w, br[g][1].w, br[g][2].w, br[g][3].w);
        }
    };
    auto readA = [&](int i, int k, int buf) -> short8 {
        int m = wm + i * 16 + lr;
        int s = ((k >> 3) ^ (m & 7)) & 7;
        return *(const short8*)(AsB[buf] + m * 128 + s * 16);
    };

    // ---- prologue: stage tile 0 into buf 0 ----
    loadB(0);
    gloadA(0, 0);
    writeB(0);         // waits br via register-dep waitcnt
    __syncthreads();   // drains gloadA (vmcnt) + writeB (lgkm)

    for (int ks = 0; ks < NSTEP; ++ks) {
        const int  c  = ks & 1;
        const bool pf = (ks + 1 < NSTEP);
        // issue next tile's loads FIRST -- in flight across the whole compute
        if (pf) { gloadA((ks + 1) * BK, c ^ 1); loadB((ks + 1) * BK); }

        #pragma unroll
        for (int kk = 0; kk < 2; ++kk) {
            int k = kk * 32 + lg * 8;
            short8 af[4], bfr[4];
            #pragma unroll
            for (int i = 0; i < 4; ++i) af[i] = readA(i, k, c);
            #pragma unroll
            for (int j = 0; j < 4; ++j)
                bfr[j] = *(const short8*)(BsB[c] + b_off(wn + j * 16 + lr, k));
            #pragma unroll
            for (int i = 0; i < 4; ++i)
                #pragma unroll
                for (int j = 0; j < 4; ++j)
                    acc[i][j] = __builtin_amdgcn_mfma_f32_16x16x32_bf16(af[i], bfr[j], acc[i][j], 0, 0, 0);
        }
        // write next B tile to the other buffer (no barrier needed: disjoint buf)
        if (pf) writeB(c ^ 1);
        __syncthreads();   // single barrier per K-step
    }

    // ---- epilogue: C/D layout col=lane&15, row=(lane>>4)*4+reg (verified) ----
    #pragma unroll
    for (int i = 0; i < 4; ++i) {
        #pragma unroll
        for (int rr = 0; rr < 4; ++rr) {
            int row = wm + i * 16 + lg * 4 + rr;
            CT* Cp = Ce + (size_t)row * N + wn + lr;
            if constexpr (sizeof(CT) == 2) {
                #pragma unroll
                for (int jp = 0; jp < 2; ++jp) {
                    float v0 = acc[i][2 * jp + 0][rr];
                    float v1 = acc[i][2 * jp + 1][rr];
                    if constexpr (RELU) {
                        v0 = v0 > 0.0f ? v0 : 0.0f;
                        v1 = v1 > 0.0f ? v1 : 0.0f;
                    }
                    uint32 pk = cvt_pk_bf16(v0, v1);
                    ((u16*)Cp)[(2 * jp + 0) * 16] = (u16)(pk & 0xffffu);
                    ((u16*)Cp)[(2 * jp + 1) * 16] = (u16)(pk >> 16);
                }
            } else {
                #pragma unroll
                for (int j = 0; j < 4; ++j) {
                    float v = acc[i][j][rr];
                    if constexpr (RELU) v = v > 0.0f ? v : 0.0f;
                    ((float*)Cp)[j * 16] = v;
                }
            }
        }
    }
}

extern "C" void kernel_launch(void* const* d_in, const int* in_sizes, int n_in,
                              void* d_out, int out_size, void* d_ws, size_t ws_size,
                              hipStream_t stream) {
    const float* x    = (const float*)d_in[0];
    // d_in[1] = gate: dead code in the reference output -- unused.
    const float* lin1 = (const float*)d_in[2];
    const float* lin2 = (const float*)d_in[3];
    float* out = (float*)d_out;

    u16* h  = (u16*)d_ws;                                     // 33.6 MB bf16
    u16* xb = (u16*)((char*)d_ws + (size_t)36 * 1024 * 1024); // 16.8 MB bf16

    dim3 blk(256);
    // x: f32 -> bf16 once (bit-identical RNE to per-tile conversion)
    cvt_bf16<<<2048, blk, 0, stream>>>(x, xb, NE * MM * DM / 4);
    // GEMM1: h = relu(x @ W1), per expert 256x2048, K=1024
    ec_gemm<ES, DM, true,  u16  ><<<NE * (MM/128) * (ES/128), blk, 0, stream>>>(xb, lin1, h);
    // GEMM2: out = h @ W2, per expert 256x1024, K=2048
    ec_gemm<DM, ES, false, float><<<NE * (MM/128) * (DM/128), blk, 0, stream>>>(h, lin2, out);
}

// Round 6
// 169.580 us; speedup vs baseline: 1.1231x; 1.0698x over previous
//
#include <hip/hip_runtime.h>
#include <hip/hip_bf16.h>

#define NE 32
#define MM 256        // tokens per expert
#define DM 1024       // dmodel
#define ES 2048       // expert size

typedef __attribute__((ext_vector_type(8))) short short8;
typedef __attribute__((ext_vector_type(4))) float f32x4;
typedef unsigned int uint32;
typedef unsigned long long u64;
typedef unsigned short u16;

// One-instruction packed f32->bf16 (RNE). D[15:0]=bf16(a), D[31:16]=bf16(b).
__device__ __forceinline__ uint32 cvt_pk_bf16(float a, float b) {
    uint32 r;
    asm("v_cvt_pk_bf16_f32 %0, %1, %2" : "=v"(r) : "v"(a), "v"(b));
    return r;
}
__device__ __forceinline__ u64 pack4(float a, float b, float c, float d) {
    return (u64)cvt_pk_bf16(a, b) | ((u64)cvt_pk_bf16(c, d) << 32);
}

// Async global->LDS, 16B per lane. LDS dest is wave-uniform base + lane*16.
__device__ __forceinline__ void gl_lds16(const void* g, void* l) {
    __builtin_amdgcn_global_load_lds(
        (const __attribute__((address_space(1))) uint32*)g,
        (__attribute__((address_space(3))) uint32*)l, 16, 0, 0);
}

// B LDS tile: bf16 [n][k], 128B rows, 16B-slot XOR swizzle (verified r1-r5).
__device__ __forceinline__ int b_off(int n, int k) {
    int X = ((n >> 2) & 7) ^ ((n & 3) << 1);
    return n * 128 + ((((k >> 3) ^ X) & 7) << 4) + (((k >> 2) & 1) << 3);
}

// Streaming f32 -> bf16 convert (for x). 16B loads / 8B stores per thread-iter.
__global__ __launch_bounds__(256) void cvt_bf16(const float* __restrict__ x,
                                                u16* __restrict__ xb, int n4) {
    int i = blockIdx.x * blockDim.x + threadIdx.x;
    int stride = gridDim.x * blockDim.x;
    for (; i < n4; i += stride) {
        float4 v = ((const float4*)x)[i];
        ((u64*)xb)[i] = pack4(v.x, v.y, v.z, v.w);
    }
}

// Grouped GEMM: C[e] = act(A[e] @ B[e]) over NE experts.
// BM=256: ONE block owns the full 256-token expert panel for its nt column,
// so each W panel is fetched from HBM exactly once BY CONSTRUCTION (the
// dominant 536 MB stream no longer depends on cross-block L2 timing).
// 512 threads / 8 waves (4Mx2N wave-tiles of 64x64). Double-buffered LDS
// (A 2x32KB + B 2x16KB = 96KB, 1 block/CU), one barrier per K-step.
// A: bf16, global_load_lds w/ source-side granule swizzle (rule #21).
// B: f32 W, reg-prefetched one step ahead, cvt_pk+transposed to LDS.
// XCD decode: all NT blocks of an expert on one XCD (A-panel L2 reuse).
template<int N, int K, bool RELU, typename CT>
__global__ __launch_bounds__(512) void ec_gemm(
    const u16* __restrict__ A,
    const float* __restrict__ B,
    CT* __restrict__ C)
{
    constexpr int BM = 256, BN = 128, BK = 64;
    constexpr int NT = N / BN;
    constexpr int NSTEP = K / BK;
    constexpr int EPX = NE / 8;   // experts per XCD

    // ---- XCD-aware decode: bid%8 = XCD (hardware round-robin) ----
    int bid   = blockIdx.x;
    int xcd   = bid & 7;
    int local = bid >> 3;
    int e     = xcd * EPX + local / NT;
    int nt    = local % NT;

    const u16*   Ae = A + (size_t)e * MM * K;
    const float* Be = B + (size_t)e * K * N + (size_t)nt * BN;
    CT*          Ce = C + (size_t)e * MM * N + (size_t)nt * BN;

    __shared__ char AsB[2][BM * BK * 2];   // 2 x 32KB bf16, linear (gload dest)
    __shared__ char BsB[2][BN * BK * 2];   // 2 x 16KB bf16 [n][k] swizzled

    const int t    = threadIdx.x;
    const int lane = t & 63;
    const int w    = t >> 6;          // 0..7
    const int wm   = (w >> 1) * 64;   // 4 wave-rows
    const int wn   = (w & 1) * 64;    // 2 wave-cols
    const int lr   = lane & 15;
    const int lg   = lane >> 4;

    // B staging thread mapping: 512 threads cover 128n x 64k in one pass
    const int bn4 = (t & 31) * 4;     // n quad
    const int bkb = (t >> 5) * 4;     // k quad (0,4,...,60)

    f32x4  acc[4][4] = {};
    float4 br[4];                     // prefetched B: 4 k-rows

    auto gloadA = [&](int kt, int buf) {
        #pragma unroll
        for (int r = 0; r < 4; ++r) {
            int reg = w * 4 + r;              // 32 x 1KB chunks
            int m   = reg * 8 + (lane >> 3);  // 0..255
            int s   = (lane & 7) ^ (m & 7);
            const u16* g = Ae + (size_t)m * K + kt + s * 8;
            gl_lds16(g, AsB[buf] + reg * 1024);
        }
    };
    auto loadB = [&](int kt) {
        const float* Bk = Be + (size_t)(kt + bkb) * N + bn4;
        br[0] = *(const float4*)(Bk);
        br[1] = *(const float4*)(Bk + N);
        br[2] = *(const float4*)(Bk + 2 * (size_t)N);
        br[3] = *(const float4*)(Bk + 3 * (size_t)N);
    };
    auto writeB = [&](int buf) {
        *(u64*)(BsB[buf] + b_off(bn4 + 0, bkb)) = pack4(br[0].x, br[1].x, br[2].x, br[3].x);
        *(u64*)(BsB[buf] + b_off(bn4 + 1, bkb)) = pack4(br[0].y, br[1].y, br[2].y, br[3].y);
        *(u64*)(BsB[buf] + b_off(bn4 + 2, bkb)) = pack4(br[0].z, br[1].z, br[2].z, br[3].z);
        *(u64*)(BsB[buf] + b_off(bn4 + 3, bkb)) = pack4(br[0].w, br[1].w, br[2].w, br[3].w);
    };
    auto readA = [&](int i, int k, int buf) -> short8 {
        int m = wm + i * 16 + lr;
        int s = ((k >> 3) ^ (m & 7)) & 7;
        return *(const short8*)(AsB[buf] + m * 128 + s * 16);
    };

    // ---- prologue: stage tile 0 into buf 0 ----
    loadB(0);
    gloadA(0, 0);
    writeB(0);         // waits br via register-dep waitcnt
    __syncthreads();   // drains gloadA (vmcnt) + writeB (lgkm)

    for (int ks = 0; ks < NSTEP; ++ks) {
        const int  c  = ks & 1;
        const bool pf = (ks + 1 < NSTEP);
        // issue next tile's loads FIRST -- in flight across the whole compute
        if (pf) { gloadA((ks + 1) * BK, c ^ 1); loadB((ks + 1) * BK); }

        #pragma unroll
        for (int kk = 0; kk < 2; ++kk) {
            int k = kk * 32 + lg * 8;
            short8 af[4], bfr[4];
            #pragma unroll
            for (int i = 0; i < 4; ++i) af[i] = readA(i, k, c);
            #pragma unroll
            for (int j = 0; j < 4; ++j)
                bfr[j] = *(const short8*)(BsB[c] + b_off(wn + j * 16 + lr, k));
            #pragma unroll
            for (int i = 0; i < 4; ++i)
                #pragma unroll
                for (int j = 0; j < 4; ++j)
                    acc[i][j] = __builtin_amdgcn_mfma_f32_16x16x32_bf16(af[i], bfr[j], acc[i][j], 0, 0, 0);
        }
        // write next B tile to the other buffer (disjoint buf: no barrier needed)
        if (pf) writeB(c ^ 1);
        __syncthreads();   // single barrier per K-step
    }

    // ---- epilogue: C/D layout col=lane&15, row=(lane>>4)*4+reg (verified) ----
    #pragma unroll
    for (int i = 0; i < 4; ++i) {
        #pragma unroll
        for (int rr = 0; rr < 4; ++rr) {
            int row = wm + i * 16 + lg * 4 + rr;
            CT* Cp = Ce + (size_t)row * N + wn + lr;
            if constexpr (sizeof(CT) == 2) {
                #pragma unroll
                for (int jp = 0; jp < 2; ++jp) {
                    float v0 = acc[i][2 * jp + 0][rr];
                    float v1 = acc[i][2 * jp + 1][rr];
                    if constexpr (RELU) {
                        v0 = v0 > 0.0f ? v0 : 0.0f;
                        v1 = v1 > 0.0f ? v1 : 0.0f;
                    }
                    uint32 pk = cvt_pk_bf16(v0, v1);
                    ((u16*)Cp)[(2 * jp + 0) * 16] = (u16)(pk & 0xffffu);
                    ((u16*)Cp)[(2 * jp + 1) * 16] = (u16)(pk >> 16);
                }
            } else {
                #pragma unroll
                for (int j = 0; j < 4; ++j) {
                    float v = acc[i][j][rr];
                    if constexpr (RELU) v = v > 0.0f ? v : 0.0f;
                    ((float*)Cp)[j * 16] = v;
                }
            }
        }
    }
}

extern "C" void kernel_launch(void* const* d_in, const int* in_sizes, int n_in,
                              void* d_out, int out_size, void* d_ws, size_t ws_size,
                              hipStream_t stream) {
    const float* x    = (const float*)d_in[0];
    // d_in[1] = gate: dead code in the reference output -- unused.
    const float* lin1 = (const float*)d_in[2];
    const float* lin2 = (const float*)d_in[3];
    float* out = (float*)d_out;

    u16* h  = (u16*)d_ws;                                     // 33.6 MB bf16
    u16* xb = (u16*)((char*)d_ws + (size_t)36 * 1024 * 1024); // 16.8 MB bf16

    // x: f32 -> bf16 once (bit-identical RNE to per-tile conversion)
    cvt_bf16<<<2048, 256, 0, stream>>>(x, xb, NE * MM * DM / 4);
    // GEMM1: h = relu(x @ W1), per expert 256x2048, K=1024 (512 blocks, 8 waves)
    ec_gemm<ES, DM, true,  u16  ><<<NE * (ES/128), 512, 0, stream>>>(xb, lin1, h);
    // GEMM2: out = h @ W2, per expert 256x1024, K=2048 (256 blocks, 8 waves)
    ec_gemm<DM, ES, false, float><<<NE * (DM/128), 512, 0, stream>>>(h, lin2, out);
}